// Round 5
// baseline (345.585 us; speedup 1.0000x reference)
//
#include <hip/hip_runtime.h>

#define DD 256
#define TTT 512
#define BB 16
#define KK 3
#define MAXO 4096
#define LN_EPS 1e-5f

// ---------------- weight transpose: wt[l][(i*K+k)*D + o] = w[l][o][i][k] ----
__global__ void k_transpose_w(const float* __restrict__ w, float* __restrict__ wt) {
    int n = blockIdx.x * blockDim.x + threadIdx.x;
    if (n >= 2 * DD * DD * KK) return;
    int o  = n & (DD - 1);
    int r  = n >> 8;          // (l*D + i)*K + k
    int k  = r % KK;
    int r2 = r / KK;          // l*D + i
    int i  = r2 & (DD - 1);
    int l  = r2 >> 8;
    wt[n] = w[(((l * DD) + o) * DD + i) * KK + k];
}

// ---------------- cumsum per batch; writes lengths (as float) + zeroes loss -
__global__ void k_cumsum(const int* __restrict__ mf, int* __restrict__ cum,
                         float* __restrict__ dout) {
    __shared__ int s[TTT];
    int b = blockIdx.x, t = threadIdx.x;   // blockDim = 512
    s[t] = mf[b * TTT + t];
    __syncthreads();
    for (int off = 1; off < TTT; off <<= 1) {
        int v = (t >= off) ? s[t - off] : 0;
        __syncthreads();
        s[t] += v;
        __syncthreads();
    }
    cum[b * TTT + t] = s[t];
    if (t == TTT - 1) dout[(size_t)BB * MAXO * DD + b] = (float)s[t];
    if (b == 0 && t == 0) dout[(size_t)BB * MAXO * DD + BB] = 0.f;
}

// ---------------- fused conv1d(K=3) + ReLU + LayerNorm (+ optional linear+MSE)
template <bool DO_LOSS>
__global__ __launch_bounds__(256) void k_conv_ln(
    const float* __restrict__ hin, float* __restrict__ hout,
    const float* __restrict__ wt,   // [(i*K+k)*D + o] for this layer
    const float* __restrict__ cb,   // conv bias [D]
    const float* __restrict__ g, const float* __restrict__ bvec,
    const float* __restrict__ lw, const float* __restrict__ lb,
    const int* __restrict__ mf, float* __restrict__ loss) {
    constexpr int TILE = 32;
    __shared__ float s_in[DD][TILE + 4];   // row stride 36 floats (144B, 16B-aligned)
    int bt  = blockIdx.x;
    int b   = bt >> 4;                      // T/TILE = 16 tiles per batch
    int t0  = (bt & 15) * TILE;
    int tid = threadIdx.x;

    // stage input rows t0-1 .. t0+32 (zero padded) ; coalesced over channels
    for (int tp = 0; tp < TILE + 2; ++tp) {
        int tg = t0 + tp - 1;
        float v = 0.f;
        if (tg >= 0 && tg < TTT) v = hin[((size_t)b * TTT + tg) * DD + tid];
        s_in[tid][tp] = v;
    }
    __syncthreads();

    int lane = tid & 63, wv = tid >> 6;
    int o0  = lane << 2;     // 4 output channels per lane
    int tr0 = wv << 3;       // 8 time rows per warp

    float4 cb4 = *(const float4*)(cb + o0);
    float acc[8][4];
#pragma unroll
    for (int r = 0; r < 8; ++r) {
        acc[r][0] = cb4.x; acc[r][1] = cb4.y; acc[r][2] = cb4.z; acc[r][3] = cb4.w;
    }

    const float4* wt4 = (const float4*)wt;
    for (int i = 0; i < DD; ++i) {
        float4 w0 = wt4[(i * 3 + 0) * 64 + lane];
        float4 w1 = wt4[(i * 3 + 1) * 64 + lane];
        float4 w2 = wt4[(i * 3 + 2) * 64 + lane];
        const float* row = &s_in[i][tr0];
        float4 a = *(const float4*)(row);
        float4 c = *(const float4*)(row + 4);
        float2 e = *(const float2*)(row + 8);
        float v[10] = {a.x, a.y, a.z, a.w, c.x, c.y, c.z, c.w, e.x, e.y};
#pragma unroll
        for (int r = 0; r < 8; ++r) {
            float x0 = v[r], x1 = v[r + 1], x2 = v[r + 2];
            acc[r][0] += x0 * w0.x + x1 * w1.x + x2 * w2.x;
            acc[r][1] += x0 * w0.y + x1 * w1.y + x2 * w2.y;
            acc[r][2] += x0 * w0.z + x1 * w1.z + x2 * w2.z;
            acc[r][3] += x0 * w0.w + x1 * w1.w + x2 * w2.w;
        }
    }

    float4 g4 = *(const float4*)(g + o0);
    float4 b4 = *(const float4*)(bvec + o0);
    float4 lw4 = make_float4(0.f, 0.f, 0.f, 0.f);
    if constexpr (DO_LOSS) lw4 = *(const float4*)(lw + o0);

    float lsum = 0.f;
#pragma unroll
    for (int r = 0; r < 8; ++r) {
        float y0 = fmaxf(acc[r][0], 0.f), y1 = fmaxf(acc[r][1], 0.f);
        float y2 = fmaxf(acc[r][2], 0.f), y3 = fmaxf(acc[r][3], 0.f);
        float s  = y0 + y1 + y2 + y3;
        float s2 = y0 * y0 + y1 * y1 + y2 * y2 + y3 * y3;
#pragma unroll
        for (int off = 1; off < 64; off <<= 1) {
            s  += __shfl_xor(s, off);
            s2 += __shfl_xor(s2, off);
        }
        float m   = s * (1.f / DD);
        float var = s2 * (1.f / DD) - m * m;
        float rs  = rsqrtf(var + LN_EPS);
        int t = t0 + tr0 + r;
        if constexpr (!DO_LOSS) {
            float4 ov;
            ov.x = (y0 - m) * rs * g4.x + b4.x;
            ov.y = (y1 - m) * rs * g4.y + b4.y;
            ov.z = (y2 - m) * rs * g4.z + b4.z;
            ov.w = (y3 - m) * rs * g4.w + b4.w;
            *(float4*)&hout[((size_t)b * TTT + t) * DD + o0] = ov;
        } else {
            float p = ((y0 - m) * rs * g4.x + b4.x) * lw4.x +
                      ((y1 - m) * rs * g4.y + b4.y) * lw4.y +
                      ((y2 - m) * rs * g4.z + b4.z) * lw4.z +
                      ((y3 - m) * rs * g4.w + b4.w) * lw4.w;
#pragma unroll
            for (int off = 1; off < 64; off <<= 1) p += __shfl_xor(p, off);
            if (lane == 0) {
                float dv = p + lb[0];
                float er = dv - (float)mf[b * TTT + t];
                lsum += er * er;
            }
        }
    }
    if constexpr (DO_LOSS) {
        if (lane == 0) atomicAdd(loss, lsum * (1.f / (BB * TTT)));
    }
}

// ---------------- length regulator: gather-expand + zero tail ---------------
__global__ __launch_bounds__(256) void k_lenreg(const float* __restrict__ x,
                                                const int* __restrict__ cum,
                                                float* __restrict__ out) {
    __shared__ int sc[TTT];
    int blk = blockIdx.x;
    int b   = blk >> 7;            // MAXO/32 = 128 tiles per batch
    int p0  = (blk & 127) << 5;
    int tid = threadIdx.x;
    sc[tid]       = cum[b * TTT + tid];
    sc[tid + 256] = cum[b * TTT + tid + 256];
    __syncthreads();
    int len  = sc[TTT - 1];
    int lane = tid & 63, wv = tid >> 6;
    const float4* x4 = (const float4*)x;
    float4* o4 = (float4*)out;
#pragma unroll
    for (int r = 0; r < 8; ++r) {
        int p = p0 + (wv << 3) + r;
        size_t oidx = ((size_t)b * MAXO + p) * 64 + lane;
        if (p < len) {
            int lo = 0, hi = TTT;
            while (lo < hi) {
                int mid = (lo + hi) >> 1;
                if (sc[mid] <= p) lo = mid + 1; else hi = mid;
            }
            int idx = min(lo, TTT - 1);
            o4[oidx] = x4[((size_t)b * TTT + idx) * 64 + lane];
        } else {
            o4[oidx] = make_float4(0.f, 0.f, 0.f, 0.f);
        }
    }
}

extern "C" void kernel_launch(void* const* d_in, const int* in_sizes, int n_in,
                              void* d_out, int out_size, void* d_ws, size_t ws_size,
                              hipStream_t stream) {
    const float* x      = (const float*)d_in[0];
    const int*   mf     = (const int*)d_in[1];
    const float* conv_w = (const float*)d_in[4];
    const float* conv_b = (const float*)d_in[5];
    const float* ln_g   = (const float*)d_in[6];
    const float* ln_b   = (const float*)d_in[7];
    const float* lin_w  = (const float*)d_in[8];
    const float* lin_b  = (const float*)d_in[9];
    float* out = (float*)d_out;

    float* wt  = (float*)d_ws;                       // 2*768*256 floats
    float* h1  = wt + 2 * DD * DD * KK;              // 16*512*256 floats
    int*   cum = (int*)(h1 + (size_t)BB * TTT * DD); // 16*512 ints

    float* lossp = out + (size_t)BB * MAXO * DD + BB;

    k_transpose_w<<<(2 * DD * DD * KK + 255) / 256, 256, 0, stream>>>(conv_w, wt);
    k_cumsum<<<BB, TTT, 0, stream>>>(mf, cum, out);
    k_conv_ln<false><<<BB * (TTT / 32), 256, 0, stream>>>(
        x, h1, wt, conv_b, ln_g, ln_b, nullptr, nullptr, nullptr, nullptr);
    k_conv_ln<true><<<BB * (TTT / 32), 256, 0, stream>>>(
        h1, nullptr, wt + DD * DD * KK, conv_b + DD, ln_g + DD, ln_b + DD,
        lin_w, lin_b, mf, lossp);
    k_lenreg<<<BB * (MAXO / 32), 256, 0, stream>>>(x, cum, out);
}

// Round 6
// 167.819 us; speedup vs baseline: 2.0593x; 2.0593x over previous
//
#include <hip/hip_runtime.h>
#include <hip/hip_bf16.h>

#define DD 256
#define TTT 512
#define BB 16
#define KK 3
#define MAXO 4096
#define LN_EPS 1e-5f
#define TPAD 514   // 512 rows + 1 zero pad row each side (per batch)
#define NKT 24     // K-steps: 768 / 32

typedef __attribute__((ext_vector_type(8))) short short8;   // bf16x8
typedef __attribute__((ext_vector_type(4))) float f32x4;

static __device__ inline short bf16r(float v) {
    __hip_bfloat16 h = __float2bfloat16(v);   // RNE rounding
    return reinterpret_cast<short&>(h);
}

// ---- pack weights into MFMA B-fragment order, bf16 -------------------------
// frag index fi = ((l*NKT + kt)*16 + nf)*64 + lane ; lane holds 8 contiguous k
// B[k][n]: n = nf*16 + (lane&15), k = kt*32 + (lane>>4)*8 + j ; k = kappa*256 + i
__global__ void k_prep_w(const float* __restrict__ w, short* __restrict__ wpk) {
    int tid = blockIdx.x * blockDim.x + threadIdx.x;
    if (tid >= 2 * NKT * 16 * 64) return;
    int lane = tid & 63;
    int rest = tid >> 6;
    int nf = rest & 15; rest >>= 4;
    int kt = rest % NKT;
    int l  = rest / NKT;
    int n     = nf * 16 + (lane & 15);
    int kbase = kt * 32 + (lane >> 4) * 8;
    short8 v;
#pragma unroll
    for (int j = 0; j < 8; ++j) {
        int k   = kbase + j;
        int kap = k >> 8;       // kappa (tap)
        int i   = k & 255;      // input channel
        v[j] = bf16r(w[(((l * DD) + n) * DD + i) * KK + kap]);
    }
    *reinterpret_cast<short8*>(wpk + (size_t)tid * 8) = v;
}

// ---- x -> padded bf16 [BB][TPAD][DD]; zero pad rows of xb AND h1b ----------
__global__ void k_prep_x(const float* __restrict__ x, short* __restrict__ xb,
                         short* __restrict__ h1b) {
    int tid = blockIdx.x * blockDim.x + threadIdx.x;
    if (tid >= BB * TPAD * DD) return;
    int r = (tid >> 8) % TPAD;
    if (r == 0 || r == TPAD - 1) {
        xb[tid] = 0; h1b[tid] = 0;
    } else {
        int c = tid & 255;
        int b = tid / (TPAD * DD);
        xb[tid] = bf16r(x[((size_t)b * TTT + (r - 1)) * DD + c]);
    }
}

// ---- cumsum per batch; writes lengths (as float) + zeroes loss -------------
__global__ void k_cumsum(const int* __restrict__ mf, int* __restrict__ cum,
                         float* __restrict__ dout) {
    __shared__ int s[TTT];
    int b = blockIdx.x, t = threadIdx.x;   // blockDim = 512
    s[t] = mf[b * TTT + t];
    __syncthreads();
    for (int off = 1; off < TTT; off <<= 1) {
        int v = (t >= off) ? s[t - off] : 0;
        __syncthreads();
        s[t] += v;
        __syncthreads();
    }
    cum[b * TTT + t] = s[t];
    if (t == TTT - 1) dout[(size_t)BB * MAXO * DD + b] = (float)s[t];
    if (b == 0 && t == 0) dout[(size_t)BB * MAXO * DD + BB] = 0.f;
}

// ---- MFMA conv(K=3) + ReLU + LN (+ linear/MSE loss) ------------------------
// grid = BB*(TTT/16) = 512 blocks, 256 threads (4 waves).
// Block: 16 t-rows x 256 out-ch. Wave wv owns n-frags wv*4..wv*4+3.
// A[t][k] (k = kappa*256+i) = contiguous bf16 window at padded row t.
template <bool DO_LOSS>
__global__ __launch_bounds__(256) void k_conv_mfma(
    const short* __restrict__ ain,   // padded bf16 [BB][TPAD][DD]
    short* __restrict__ aout,        // padded bf16 out (layer 1) or nullptr
    const short8* __restrict__ bp,   // packed weights, this layer
    const float* __restrict__ cb,    // conv bias [DD]
    const float* __restrict__ g, const float* __restrict__ bvec,
    const float* __restrict__ lw, const float* __restrict__ lb,
    const int* __restrict__ mf, float* __restrict__ loss) {
    __shared__ float yt[16][260];    // stride 260: conflict-free epilogue
    int bt = blockIdx.x;
    int b  = bt >> 5;
    int t0 = (bt & 31) << 4;
    int tid = threadIdx.x;
    int lane = tid & 63, wv = tid >> 6;
    int mrow = lane & 15;            // A row / C col index
    int kg   = lane >> 4;            // k-group

    const short* Ab = ain + ((size_t)b * TPAD + t0 + mrow) * DD + kg * 8;
    f32x4 acc0 = {0.f,0.f,0.f,0.f}, acc1 = acc0, acc2 = acc0, acc3 = acc0;
    const short8* bw = bp + (size_t)wv * 4 * 64 + lane;

    for (int kt = 0; kt < NKT; ++kt) {
        short8 a  = *reinterpret_cast<const short8*>(Ab + kt * 32);
        short8 b0 = bw[0];
        short8 b1 = bw[64];
        short8 b2 = bw[128];
        short8 b3 = bw[192];
        acc0 = __builtin_amdgcn_mfma_f32_16x16x32_bf16(a, b0, acc0, 0, 0, 0);
        acc1 = __builtin_amdgcn_mfma_f32_16x16x32_bf16(a, b1, acc1, 0, 0, 0);
        acc2 = __builtin_amdgcn_mfma_f32_16x16x32_bf16(a, b2, acc2, 0, 0, 0);
        acc3 = __builtin_amdgcn_mfma_f32_16x16x32_bf16(a, b3, acc3, 0, 0, 0);
        bw += 16 * 64;
    }

    // bias + ReLU -> LDS tile. C layout: col=lane&15, row=kg*4+reg (m89-verified).
#define EPI(F, ACC) { int c = ((wv * 4 + F) << 4) + mrow; float bias = cb[c];   \
        yt[kg * 4 + 0][c] = fmaxf(ACC[0] + bias, 0.f);                          \
        yt[kg * 4 + 1][c] = fmaxf(ACC[1] + bias, 0.f);                          \
        yt[kg * 4 + 2][c] = fmaxf(ACC[2] + bias, 0.f);                          \
        yt[kg * 4 + 3][c] = fmaxf(ACC[3] + bias, 0.f); }
    EPI(0, acc0) EPI(1, acc1) EPI(2, acc2) EPI(3, acc3)
#undef EPI
    __syncthreads();

    // LN over 256 cols; wave wv owns rows wv*4..wv*4+3; lane covers cols 2*lane,
    // 2*lane+1, +128, +129 (float2 LDS reads, short2 coalesced stores).
    float lsum = 0.f;
    int c0 = lane << 1;
#pragma unroll
    for (int q = 0; q < 4; ++q) {
        int r = wv * 4 + q;
        float2 vA = *reinterpret_cast<float2*>(&yt[r][c0]);
        float2 vB = *reinterpret_cast<float2*>(&yt[r][c0 + 128]);
        float s  = vA.x + vA.y + vB.x + vB.y;
        float s2 = vA.x*vA.x + vA.y*vA.y + vB.x*vB.x + vB.y*vB.y;
#pragma unroll
        for (int off = 1; off < 64; off <<= 1) {
            s  += __shfl_xor(s, off);
            s2 += __shfl_xor(s2, off);
        }
        float mean = s * (1.f / DD);
        float var  = s2 * (1.f / DD) - mean * mean;
        float rs   = rsqrtf(var + LN_EPS);
        float2 gA = *reinterpret_cast<const float2*>(&g[c0]);
        float2 gB = *reinterpret_cast<const float2*>(&g[c0 + 128]);
        float2 bA = *reinterpret_cast<const float2*>(&bvec[c0]);
        float2 bB = *reinterpret_cast<const float2*>(&bvec[c0 + 128]);
        float oAx = (vA.x - mean) * rs * gA.x + bA.x;
        float oAy = (vA.y - mean) * rs * gA.y + bA.y;
        float oBx = (vB.x - mean) * rs * gB.x + bB.x;
        float oBy = (vB.y - mean) * rs * gB.y + bB.y;
        if constexpr (!DO_LOSS) {
            size_t rowb = ((size_t)b * TPAD + t0 + r + 1) * DD;
            short2 sA, sB;
            sA.x = bf16r(oAx); sA.y = bf16r(oAy);
            sB.x = bf16r(oBx); sB.y = bf16r(oBy);
            *reinterpret_cast<short2*>(&aout[rowb + c0])       = sA;
            *reinterpret_cast<short2*>(&aout[rowb + c0 + 128]) = sB;
        } else {
            float2 lA = *reinterpret_cast<const float2*>(&lw[c0]);
            float2 lB = *reinterpret_cast<const float2*>(&lw[c0 + 128]);
            float p = oAx * lA.x + oAy * lA.y + oBx * lB.x + oBy * lB.y;
#pragma unroll
            for (int off = 1; off < 64; off <<= 1) p += __shfl_xor(p, off);
            if (lane == 0) {
                float dv = p + lb[0];
                float er = dv - (float)mf[b * TTT + t0 + r];
                lsum += er * er;
            }
        }
    }
    if constexpr (DO_LOSS) {
        if (lane == 0) atomicAdd(loss, lsum * (1.f / (BB * TTT)));
    }
}

// ---- length regulator: gather-expand + zero tail ---------------------------
__global__ __launch_bounds__(256) void k_lenreg(const float* __restrict__ x,
                                                const int* __restrict__ cum,
                                                float* __restrict__ out) {
    __shared__ int sc[TTT];
    int blk = blockIdx.x;
    int b   = blk >> 7;            // MAXO/32 = 128 tiles per batch
    int p0  = (blk & 127) << 5;
    int tid = threadIdx.x;
    sc[tid]       = cum[b * TTT + tid];
    sc[tid + 256] = cum[b * TTT + tid + 256];
    __syncthreads();
    int len  = sc[TTT - 1];
    int lane = tid & 63, wv = tid >> 6;
    const float4* x4 = (const float4*)x;
    float4* o4 = (float4*)out;
#pragma unroll
    for (int r = 0; r < 8; ++r) {
        int p = p0 + (wv << 3) + r;
        size_t oidx = ((size_t)b * MAXO + p) * 64 + lane;
        if (p < len) {
            int lo = 0, hi = TTT;
            while (lo < hi) {
                int mid = (lo + hi) >> 1;
                if (sc[mid] <= p) lo = mid + 1; else hi = mid;
            }
            int idx = min(lo, TTT - 1);
            o4[oidx] = x4[((size_t)b * TTT + idx) * 64 + lane];
        } else {
            o4[oidx] = make_float4(0.f, 0.f, 0.f, 0.f);
        }
    }
}

extern "C" void kernel_launch(void* const* d_in, const int* in_sizes, int n_in,
                              void* d_out, int out_size, void* d_ws, size_t ws_size,
                              hipStream_t stream) {
    const float* x      = (const float*)d_in[0];
    const int*   mf     = (const int*)d_in[1];
    const float* conv_w = (const float*)d_in[4];
    const float* conv_b = (const float*)d_in[5];
    const float* ln_g   = (const float*)d_in[6];
    const float* ln_b   = (const float*)d_in[7];
    const float* lin_w  = (const float*)d_in[8];
    const float* lin_b  = (const float*)d_in[9];
    float* out = (float*)d_out;

    short* wpk = (short*)d_ws;                        // 2*24*16*64*8 shorts = 786 KB
    short* xb  = wpk + (size_t)2 * NKT * 16 * 64 * 8; // 16*514*256 bf16 = 4.2 MB
    short* h1b = xb + (size_t)BB * TPAD * DD;         // 4.2 MB
    int*   cum = (int*)(h1b + (size_t)BB * TPAD * DD);

    float* lossp = out + (size_t)BB * MAXO * DD + BB;

    k_prep_w<<<(2 * NKT * 16 * 64 + 255) / 256, 256, 0, stream>>>(conv_w, wpk);
    k_prep_x<<<(BB * TPAD * DD + 255) / 256, 256, 0, stream>>>(x, xb, h1b);
    k_cumsum<<<BB, TTT, 0, stream>>>(mf, cum, out);
    k_conv_mfma<false><<<BB * (TTT / 16), 256, 0, stream>>>(
        xb, h1b, (const short8*)wpk, conv_b, ln_g, ln_b,
        nullptr, nullptr, nullptr, nullptr);
    k_conv_mfma<true><<<BB * (TTT / 16), 256, 0, stream>>>(
        h1b, nullptr, (const short8*)wpk + (size_t)NKT * 16 * 64,
        conv_b + DD, ln_g + DD, ln_b + DD, lin_w, lin_b, mf, lossp);
    k_lenreg<<<BB * (MAXO / 32), 256, 0, stream>>>(x, cum, out);
}

// Round 7
// 165.795 us; speedup vs baseline: 2.0844x; 1.0122x over previous
//
#include <hip/hip_runtime.h>
#include <hip/hip_bf16.h>

#define DD 256
#define TTT 512
#define BB 16
#define KK 3
#define MAXO 4096
#define LN_EPS 1e-5f
#define TPAD 514   // 512 rows + 1 zero pad row each side (per batch)
#define NKT 24     // K-steps: 768 / 32

typedef __attribute__((ext_vector_type(8))) short short8;   // bf16x8
typedef __attribute__((ext_vector_type(4))) float f32x4;

static __device__ inline short bf16r(float v) {
    __hip_bfloat16 h = __float2bfloat16(v);   // RNE rounding
    return reinterpret_cast<short&>(h);
}

// ---- pack weights into MFMA B-fragment order, bf16 -------------------------
__global__ void k_prep_w(const float* __restrict__ w, short* __restrict__ wpk) {
    int tid = blockIdx.x * blockDim.x + threadIdx.x;
    if (tid >= 2 * NKT * 16 * 64) return;
    int lane = tid & 63;
    int rest = tid >> 6;
    int nf = rest & 15; rest >>= 4;
    int kt = rest % NKT;
    int l  = rest / NKT;
    int n     = nf * 16 + (lane & 15);
    int kbase = kt * 32 + (lane >> 4) * 8;
    short8 v;
#pragma unroll
    for (int j = 0; j < 8; ++j) {
        int k   = kbase + j;
        int kap = k >> 8;       // kappa (tap)
        int i   = k & 255;      // input channel
        v[j] = bf16r(w[(((l * DD) + n) * DD + i) * KK + kap]);
    }
    *reinterpret_cast<short8*>(wpk + (size_t)tid * 8) = v;
}

// ---- x -> padded bf16 [BB][TPAD][DD]; zero pad rows of xb AND h1b ----------
__global__ void k_prep_x(const float* __restrict__ x, short* __restrict__ xb,
                         short* __restrict__ h1b) {
    int tid = blockIdx.x * blockDim.x + threadIdx.x;
    if (tid >= BB * TPAD * DD) return;
    int r = (tid >> 8) % TPAD;
    if (r == 0 || r == TPAD - 1) {
        xb[tid] = 0; h1b[tid] = 0;
    } else {
        int c = tid & 255;
        int b = tid / (TPAD * DD);
        xb[tid] = bf16r(x[((size_t)b * TTT + (r - 1)) * DD + c]);
    }
}

// ---- cumsum per batch; writes lengths + zeroes loss + scatters idx ---------
__global__ void k_cumsum(const int* __restrict__ mf, int* __restrict__ cum,
                         float* __restrict__ dout, int* __restrict__ idxb) {
    __shared__ int s[TTT];
    int b = blockIdx.x, t = threadIdx.x;   // blockDim = 512
    s[t] = mf[b * TTT + t];
    __syncthreads();
    for (int off = 1; off < TTT; off <<= 1) {
        int v = (t >= off) ? s[t - off] : 0;
        __syncthreads();
        s[t] += v;
        __syncthreads();
    }
    cum[b * TTT + t] = s[t];
    // inverse scatter: idx[p] = t for p in [cum[t-1], cum[t])   (searchsorted 'right')
    int hi = s[t];
    int lo = (t == 0) ? 0 : s[t - 1];
    for (int p = lo; p < hi; ++p) idxb[b * MAXO + p] = t;
    if (t == TTT - 1) dout[(size_t)BB * MAXO * DD + b] = (float)s[t];
    if (b == 0 && t == 0) dout[(size_t)BB * MAXO * DD + BB] = 0.f;
}

// ---- MFMA conv(K=3) + ReLU + LN (+ linear/MSE loss) ------------------------
template <bool DO_LOSS>
__global__ __launch_bounds__(256) void k_conv_mfma(
    const short* __restrict__ ain,   // padded bf16 [BB][TPAD][DD]
    short* __restrict__ aout,        // padded bf16 out (layer 1) or nullptr
    const short8* __restrict__ bp,   // packed weights, this layer
    const float* __restrict__ cb,    // conv bias [DD]
    const float* __restrict__ g, const float* __restrict__ bvec,
    const float* __restrict__ lw, const float* __restrict__ lb,
    const int* __restrict__ mf, float* __restrict__ loss) {
    __shared__ float yt[16][260];    // stride 260: conflict-free epilogue
    int bt = blockIdx.x;
    int b  = bt >> 5;
    int t0 = (bt & 31) << 4;
    int tid = threadIdx.x;
    int lane = tid & 63, wv = tid >> 6;
    int mrow = lane & 15;            // A row / C col index
    int kg   = lane >> 4;            // k-group

    const short* Ab = ain + ((size_t)b * TPAD + t0 + mrow) * DD + kg * 8;
    f32x4 acc0 = {0.f,0.f,0.f,0.f}, acc1 = acc0, acc2 = acc0, acc3 = acc0;
    const short8* bw = bp + (size_t)wv * 4 * 64 + lane;

    for (int kt = 0; kt < NKT; ++kt) {
        short8 a  = *reinterpret_cast<const short8*>(Ab + kt * 32);
        short8 b0 = bw[0];
        short8 b1 = bw[64];
        short8 b2 = bw[128];
        short8 b3 = bw[192];
        acc0 = __builtin_amdgcn_mfma_f32_16x16x32_bf16(a, b0, acc0, 0, 0, 0);
        acc1 = __builtin_amdgcn_mfma_f32_16x16x32_bf16(a, b1, acc1, 0, 0, 0);
        acc2 = __builtin_amdgcn_mfma_f32_16x16x32_bf16(a, b2, acc2, 0, 0, 0);
        acc3 = __builtin_amdgcn_mfma_f32_16x16x32_bf16(a, b3, acc3, 0, 0, 0);
        bw += 16 * 64;
    }

    // bias + ReLU -> LDS tile. C layout: col=lane&15, row=kg*4+reg (m89-verified).
#define EPI(F, ACC) { int c = ((wv * 4 + F) << 4) + mrow; float bias = cb[c];   \
        yt[kg * 4 + 0][c] = fmaxf(ACC[0] + bias, 0.f);                          \
        yt[kg * 4 + 1][c] = fmaxf(ACC[1] + bias, 0.f);                          \
        yt[kg * 4 + 2][c] = fmaxf(ACC[2] + bias, 0.f);                          \
        yt[kg * 4 + 3][c] = fmaxf(ACC[3] + bias, 0.f); }
    EPI(0, acc0) EPI(1, acc1) EPI(2, acc2) EPI(3, acc3)
#undef EPI
    __syncthreads();

    float lsum = 0.f;
    int c0 = lane << 1;
#pragma unroll
    for (int q = 0; q < 4; ++q) {
        int r = wv * 4 + q;
        float2 vA = *reinterpret_cast<float2*>(&yt[r][c0]);
        float2 vB = *reinterpret_cast<float2*>(&yt[r][c0 + 128]);
        float s  = vA.x + vA.y + vB.x + vB.y;
        float s2 = vA.x*vA.x + vA.y*vA.y + vB.x*vB.x + vB.y*vB.y;
#pragma unroll
        for (int off = 1; off < 64; off <<= 1) {
            s  += __shfl_xor(s, off);
            s2 += __shfl_xor(s2, off);
        }
        float mean = s * (1.f / DD);
        float var  = s2 * (1.f / DD) - mean * mean;
        float rs   = rsqrtf(var + LN_EPS);
        float2 gA = *reinterpret_cast<const float2*>(&g[c0]);
        float2 gB = *reinterpret_cast<const float2*>(&g[c0 + 128]);
        float2 bA = *reinterpret_cast<const float2*>(&bvec[c0]);
        float2 bB = *reinterpret_cast<const float2*>(&bvec[c0 + 128]);
        float oAx = (vA.x - mean) * rs * gA.x + bA.x;
        float oAy = (vA.y - mean) * rs * gA.y + bA.y;
        float oBx = (vB.x - mean) * rs * gB.x + bB.x;
        float oBy = (vB.y - mean) * rs * gB.y + bB.y;
        if constexpr (!DO_LOSS) {
            size_t rowb = ((size_t)b * TPAD + t0 + r + 1) * DD;
            short2 sA, sB;
            sA.x = bf16r(oAx); sA.y = bf16r(oAy);
            sB.x = bf16r(oBx); sB.y = bf16r(oBy);
            *reinterpret_cast<short2*>(&aout[rowb + c0])       = sA;
            *reinterpret_cast<short2*>(&aout[rowb + c0 + 128]) = sB;
        } else {
            float2 lA = *reinterpret_cast<const float2*>(&lw[c0]);
            float2 lB = *reinterpret_cast<const float2*>(&lw[c0 + 128]);
            float p = oAx * lA.x + oAy * lA.y + oBx * lB.x + oBy * lB.y;
#pragma unroll
            for (int off = 1; off < 64; off <<= 1) p += __shfl_xor(p, off);
            if (lane == 0) {
                float dv = p + lb[0];
                float er = dv - (float)mf[b * TTT + t0 + r];
                lsum += er * er;
            }
        }
    }
    if constexpr (DO_LOSS) {
        if (lane == 0) atomicAdd(loss, lsum * (1.f / (BB * TTT)));
    }
}

// ---- length regulator: precomputed-idx gather + zero tail ------------------
__global__ __launch_bounds__(256) void k_lenreg2(const float* __restrict__ x,
                                                 const int* __restrict__ cum,
                                                 const int* __restrict__ idxb,
                                                 float* __restrict__ out) {
    int blk = blockIdx.x;
    int b   = blk >> 7;            // MAXO/32 = 128 tiles per batch
    int p0  = (blk & 127) << 5;
    int tid = threadIdx.x;
    int lane = tid & 63, wv = tid >> 6;
    int len = cum[b * TTT + TTT - 1];   // L2-hit broadcast
    const float4* x4 = (const float4*)x;
    float4* o4 = (float4*)out;
#pragma unroll
    for (int r = 0; r < 8; ++r) {
        int p = p0 + (wv << 3) + r;
        size_t oidx = ((size_t)b * MAXO + p) * 64 + lane;
        if (p < len) {
            int idx = idxb[b * MAXO + p];      // wave-uniform broadcast load
            o4[oidx] = x4[((size_t)b * TTT + idx) * 64 + lane];
        } else {
            o4[oidx] = make_float4(0.f, 0.f, 0.f, 0.f);
        }
    }
}

extern "C" void kernel_launch(void* const* d_in, const int* in_sizes, int n_in,
                              void* d_out, int out_size, void* d_ws, size_t ws_size,
                              hipStream_t stream) {
    const float* x      = (const float*)d_in[0];
    const int*   mf     = (const int*)d_in[1];
    const float* conv_w = (const float*)d_in[4];
    const float* conv_b = (const float*)d_in[5];
    const float* ln_g   = (const float*)d_in[6];
    const float* ln_b   = (const float*)d_in[7];
    const float* lin_w  = (const float*)d_in[8];
    const float* lin_b  = (const float*)d_in[9];
    float* out = (float*)d_out;

    short* wpk = (short*)d_ws;                        // 786 KB
    short* xb  = wpk + (size_t)2 * NKT * 16 * 64 * 8; // 4.2 MB
    short* h1b = xb + (size_t)BB * TPAD * DD;         // 4.2 MB
    int*   cum  = (int*)(h1b + (size_t)BB * TPAD * DD);  // 32 KB
    int*   idxb = cum + BB * TTT;                        // 262 KB

    float* lossp = out + (size_t)BB * MAXO * DD + BB;

    k_prep_w<<<(2 * NKT * 16 * 64 + 255) / 256, 256, 0, stream>>>(conv_w, wpk);
    k_prep_x<<<(BB * TPAD * DD + 255) / 256, 256, 0, stream>>>(x, xb, h1b);
    k_cumsum<<<BB, TTT, 0, stream>>>(mf, cum, out, idxb);
    k_conv_mfma<false><<<BB * (TTT / 16), 256, 0, stream>>>(
        xb, h1b, (const short8*)wpk, conv_b, ln_g, ln_b,
        nullptr, nullptr, nullptr, nullptr);
    k_conv_mfma<true><<<BB * (TTT / 16), 256, 0, stream>>>(
        h1b, nullptr, (const short8*)wpk + (size_t)NKT * 16 * 64,
        conv_b + DD, ln_g + DD, ln_b + DD, lin_w, lin_b, mf, lossp);
    k_lenreg2<<<BB * (MAXO / 32), 256, 0, stream>>>(x, cum, idxb, out);
}

// Round 9
// 158.578 us; speedup vs baseline: 2.1793x; 1.0455x over previous
//
#include <hip/hip_runtime.h>
#include <hip/hip_bf16.h>

#define DD 256
#define TTT 512
#define BB 16
#define KK 3
#define MAXO 4096
#define LN_EPS 1e-5f
#define TPAD 514   // 512 rows + 1 zero pad row each side (per batch)
#define NKT 24     // K-steps: 768 / 32

typedef __attribute__((ext_vector_type(8))) short short8;   // bf16x8
typedef __attribute__((ext_vector_type(4))) float f32x4;

static __device__ inline short bf16r(float v) {
    __hip_bfloat16 h = __float2bfloat16(v);   // RNE rounding
    return reinterpret_cast<short&>(h);
}

// ---- fused prep: blocks [0,16) cumsum+scatter | [16,112) weight pack |
//                  [112,4224) x->bf16 pad.  blockDim = 512 for all roles.
__global__ __launch_bounds__(512) void k_prep_all(
    const float* __restrict__ x, const int* __restrict__ mf,
    const float* __restrict__ w, short* __restrict__ wpk,
    short* __restrict__ xb, short* __restrict__ h1b,
    int* __restrict__ cum, int* __restrict__ idxb, float* __restrict__ dout) {
    __shared__ int s[TTT];
    int blk = blockIdx.x;
    if (blk < 16) {
        // ---- cumsum per batch; lengths (as float) + loss zero + idx scatter
        int b = blk, t = threadIdx.x;
        s[t] = mf[b * TTT + t];
        __syncthreads();
        for (int off = 1; off < TTT; off <<= 1) {
            int v = (t >= off) ? s[t - off] : 0;
            __syncthreads();
            s[t] += v;
            __syncthreads();
        }
        cum[b * TTT + t] = s[t];
        int hi = s[t];
        int lo = (t == 0) ? 0 : s[t - 1];
        for (int p = lo; p < hi; ++p) idxb[b * MAXO + p] = t;
        if (t == TTT - 1) dout[(size_t)BB * MAXO * DD + b] = (float)s[t];
        if (b == 0 && t == 0) dout[(size_t)BB * MAXO * DD + BB] = 0.f;
    } else if (blk < 112) {
        // ---- pack weights into MFMA B-fragment order (96*512 = 49152 exact)
        int tid = (blk - 16) * 512 + threadIdx.x;
        int lane = tid & 63;
        int rest = tid >> 6;
        int nf = rest & 15; rest >>= 4;
        int kt = rest % NKT;
        int l  = rest / NKT;
        int n     = nf * 16 + (lane & 15);
        int kbase = kt * 32 + (lane >> 4) * 8;
        short8 v;
#pragma unroll
        for (int j = 0; j < 8; ++j) {
            int k   = kbase + j;
            int kap = k >> 8;       // tap
            int i   = k & 255;      // input channel
            v[j] = bf16r(w[(((l * DD) + n) * DD + i) * KK + kap]);
        }
        *reinterpret_cast<short8*>(wpk + (size_t)tid * 8) = v;
    } else {
        // ---- x -> padded bf16 [BB][TPAD][DD]; zero pad rows of xb AND h1b
        int tid = (blk - 112) * 512 + threadIdx.x;   // 4112*512 = BB*TPAD*DD exact
        int r = (tid >> 8) % TPAD;
        if (r == 0 || r == TPAD - 1) {
            xb[tid] = 0; h1b[tid] = 0;
        } else {
            int c = tid & 255;
            int b = tid / (TPAD * DD);
            xb[tid] = bf16r(x[((size_t)b * TTT + (r - 1)) * DD + c]);
        }
    }
}

// ---- conv core (MFMA) + ReLU + LN (+ linear/MSE loss), callable body -------
template <bool DO_LOSS>
static __device__ inline void conv_body(
    int bt, int tid,
    const short* __restrict__ ain, short* __restrict__ aout,
    const short8* __restrict__ bp, const float* __restrict__ cb,
    const float* __restrict__ g, const float* __restrict__ bvec,
    const float* __restrict__ lw, const float* __restrict__ lb,
    const int* __restrict__ mf, float* __restrict__ loss,
    float (*yt)[260]) {
    int b  = bt >> 5;
    int t0 = (bt & 31) << 4;
    int lane = tid & 63, wv = tid >> 6;
    int mrow = lane & 15;            // A row / C col index
    int kg   = lane >> 4;            // k-group

    const short* Ab = ain + ((size_t)b * TPAD + t0 + mrow) * DD + kg * 8;
    f32x4 acc0 = {0.f,0.f,0.f,0.f}, acc1 = acc0, acc2 = acc0, acc3 = acc0;
    const short8* bw = bp + (size_t)wv * 4 * 64 + lane;

    for (int kt = 0; kt < NKT; ++kt) {
        short8 a  = *reinterpret_cast<const short8*>(Ab + kt * 32);
        short8 b0 = bw[0];
        short8 b1 = bw[64];
        short8 b2 = bw[128];
        short8 b3 = bw[192];
        acc0 = __builtin_amdgcn_mfma_f32_16x16x32_bf16(a, b0, acc0, 0, 0, 0);
        acc1 = __builtin_amdgcn_mfma_f32_16x16x32_bf16(a, b1, acc1, 0, 0, 0);
        acc2 = __builtin_amdgcn_mfma_f32_16x16x32_bf16(a, b2, acc2, 0, 0, 0);
        acc3 = __builtin_amdgcn_mfma_f32_16x16x32_bf16(a, b3, acc3, 0, 0, 0);
        bw += 16 * 64;
    }

    // bias + ReLU -> LDS tile. C layout: col=lane&15, row=kg*4+reg (m89-verified).
#define EPI(F, ACC) { int c = ((wv * 4 + F) << 4) + mrow; float bias = cb[c];   \
        yt[kg * 4 + 0][c] = fmaxf(ACC[0] + bias, 0.f);                          \
        yt[kg * 4 + 1][c] = fmaxf(ACC[1] + bias, 0.f);                          \
        yt[kg * 4 + 2][c] = fmaxf(ACC[2] + bias, 0.f);                          \
        yt[kg * 4 + 3][c] = fmaxf(ACC[3] + bias, 0.f); }
    EPI(0, acc0) EPI(1, acc1) EPI(2, acc2) EPI(3, acc3)
#undef EPI
    __syncthreads();

    float lsum = 0.f;
    int c0 = lane << 1;
#pragma unroll
    for (int q = 0; q < 4; ++q) {
        int r = wv * 4 + q;
        float2 vA = *reinterpret_cast<float2*>(&yt[r][c0]);
        float2 vB = *reinterpret_cast<float2*>(&yt[r][c0 + 128]);
        float s  = vA.x + vA.y + vB.x + vB.y;
        float s2 = vA.x*vA.x + vA.y*vA.y + vB.x*vB.x + vB.y*vB.y;
#pragma unroll
        for (int off = 1; off < 64; off <<= 1) {
            s  += __shfl_xor(s, off);
            s2 += __shfl_xor(s2, off);
        }
        float mean = s * (1.f / DD);
        float var  = s2 * (1.f / DD) - mean * mean;
        float rs   = rsqrtf(var + LN_EPS);
        float2 gA = *reinterpret_cast<const float2*>(&g[c0]);
        float2 gB = *reinterpret_cast<const float2*>(&g[c0 + 128]);
        float2 bA = *reinterpret_cast<const float2*>(&bvec[c0]);
        float2 bB = *reinterpret_cast<const float2*>(&bvec[c0 + 128]);
        float oAx = (vA.x - mean) * rs * gA.x + bA.x;
        float oAy = (vA.y - mean) * rs * gA.y + bA.y;
        float oBx = (vB.x - mean) * rs * gB.x + bB.x;
        float oBy = (vB.y - mean) * rs * gB.y + bB.y;
        if constexpr (!DO_LOSS) {
            size_t rowb = ((size_t)b * TPAD + t0 + r + 1) * DD;
            short2 sA, sB;
            sA.x = bf16r(oAx); sA.y = bf16r(oAy);
            sB.x = bf16r(oBx); sB.y = bf16r(oBy);
            *reinterpret_cast<short2*>(&aout[rowb + c0])       = sA;
            *reinterpret_cast<short2*>(&aout[rowb + c0 + 128]) = sB;
        } else {
            float2 lA = *reinterpret_cast<const float2*>(&lw[c0]);
            float2 lB = *reinterpret_cast<const float2*>(&lw[c0 + 128]);
            float p = oAx * lA.x + oAy * lA.y + oBx * lB.x + oBy * lB.y;
#pragma unroll
            for (int off = 1; off < 64; off <<= 1) p += __shfl_xor(p, off);
            if (lane == 0) {
                float dv = p + lb[0];
                float er = dv - (float)mf[b * TTT + t0 + r];
                lsum += er * er;
            }
        }
    }
    if constexpr (DO_LOSS) {
        if (lane == 0) atomicAdd(loss, lsum * (1.f / (BB * TTT)));
    }
}

// ---- mid: blocks [0,512) conv layer 1 | [512,2560) length regulator --------
__global__ __launch_bounds__(256) void k_mid(
    const short* __restrict__ xb, short* __restrict__ h1b,
    const short8* __restrict__ bp, const float* __restrict__ cb,
    const float* __restrict__ g, const float* __restrict__ bvec,
    const float* __restrict__ x, const int* __restrict__ cum,
    const int* __restrict__ idxb, float* __restrict__ out) {
    __shared__ float yt[16][260];
    int blk = blockIdx.x;
    int tid = threadIdx.x;
    if (blk < 512) {
        conv_body<false>(blk, tid, xb, h1b, bp, cb, g, bvec,
                         nullptr, nullptr, nullptr, nullptr, yt);
    } else {
        int lrb = blk - 512;
        int b   = lrb >> 7;            // MAXO/32 = 128 tiles per batch
        int p0  = (lrb & 127) << 5;
        int lane = tid & 63, wv = tid >> 6;
        int len = cum[b * TTT + TTT - 1];
        const float4* x4 = (const float4*)x;
        float4* o4 = (float4*)out;
#pragma unroll
        for (int r = 0; r < 8; ++r) {
            int p = p0 + (wv << 3) + r;
            size_t oidx = ((size_t)b * MAXO + p) * 64 + lane;
            if (p < len) {
                int idx = idxb[b * MAXO + p];      // wave-uniform broadcast
                o4[oidx] = x4[((size_t)b * TTT + idx) * 64 + lane];
            } else {
                o4[oidx] = make_float4(0.f, 0.f, 0.f, 0.f);
            }
        }
    }
}

// ---- final: conv layer 2 + linear + MSE loss -------------------------------
__global__ __launch_bounds__(256) void k_final(
    const short* __restrict__ h1b, const short8* __restrict__ bp,
    const float* __restrict__ cb, const float* __restrict__ g,
    const float* __restrict__ bvec, const float* __restrict__ lw,
    const float* __restrict__ lb, const int* __restrict__ mf,
    float* __restrict__ loss) {
    __shared__ float yt[16][260];
    conv_body<true>(blockIdx.x, threadIdx.x, h1b, nullptr, bp, cb, g, bvec,
                    lw, lb, mf, loss, yt);
}

extern "C" void kernel_launch(void* const* d_in, const int* in_sizes, int n_in,
                              void* d_out, int out_size, void* d_ws, size_t ws_size,
                              hipStream_t stream) {
    const float* x      = (const float*)d_in[0];
    const int*   mf     = (const int*)d_in[1];
    const float* conv_w = (const float*)d_in[4];
    const float* conv_b = (const float*)d_in[5];
    const float* ln_g   = (const float*)d_in[6];
    const float* ln_b   = (const float*)d_in[7];
    const float* lin_w  = (const float*)d_in[8];
    const float* lin_b  = (const float*)d_in[9];
    float* out = (float*)d_out;

    short* wpk = (short*)d_ws;                        // 786 KB
    short* xb  = wpk + (size_t)2 * NKT * 16 * 64 * 8; // 4.2 MB
    short* h1b = xb + (size_t)BB * TPAD * DD;         // 4.2 MB
    int*   cum  = (int*)(h1b + (size_t)BB * TPAD * DD);  // 32 KB
    int*   idxb = cum + BB * TTT;                        // 262 KB

    float* lossp = out + (size_t)BB * MAXO * DD + BB;

    k_prep_all<<<16 + 96 + 4112, 512, 0, stream>>>(
        x, mf, conv_w, wpk, xb, h1b, cum, idxb, out);
    k_mid<<<512 + BB * (MAXO / 32), 256, 0, stream>>>(
        xb, h1b, (const short8*)wpk, conv_b, ln_g, ln_b,
        x, cum, idxb, out);
    k_final<<<512, 256, 0, stream>>>(
        h1b, (const short8*)wpk + (size_t)NKT * 16 * 64,
        conv_b + DD, ln_g + DD, ln_b + DD, lin_w, lin_b, mf, lossp);
}